// Round 1
// baseline (11508.153 us; speedup 1.0000x reference)
//
#include <hip/hip_runtime.h>

#define BB 64
#define TT 512
#define EE 512
#define RR 2048
#define NWG 64
#define CPW 32   // columns per scan workgroup

typedef _Float16 f16;
typedef f16 f16x8 __attribute__((ext_vector_type(8)));
typedef float f32x4 __attribute__((ext_vector_type(4)));

__device__ __forceinline__ void gload16(const void* g, void* l) {
  __builtin_amdgcn_global_load_lds(
      (const __attribute__((address_space(1))) void*)g,
      (__attribute__((address_space(3))) void*)l, 16, 0, 0);
}

__device__ __forceinline__ float fast_tanh(float v) {
  float e = __expf(2.0f * v);
  return 1.0f - 2.0f / (e + 1.0f);
}

// ---------------- prep kernels ----------------

__global__ void prep_emb(const int* __restrict__ x, const float* __restrict__ ew,
                         f16* __restrict__ emb) {
  const int row = blockIdx.x;            // token index 0..32767 (b*T + t)
  const int tok = x[row];
  const float4* src = (const float4*)(ew + (size_t)tok * EE);
  f16* dst = emb + (size_t)row * EE;
  const int i = threadIdx.x;             // 128 threads, 4 f16 each
  float4 v = src[i];
  union { f16 h[4]; unsigned long long u; } p;
  p.h[0] = (f16)v.x; p.h[1] = (f16)v.y; p.h[2] = (f16)v.z; p.h[3] = (f16)v.w;
  ((unsigned long long*)dst)[i] = p.u;
}

__global__ void prep_winT(const float* __restrict__ Win, f16* __restrict__ WinT) {
  const int i = blockIdx.x * blockDim.x + threadIdx.x;  // over EE*RR
  if (i < EE * RR) {
    const int k = i / RR, n = i % RR;
    WinT[(size_t)n * EE + k] = (f16)Win[i];
  }
}

// ---------------- projection GEMM: U[t][b][n] = emb[b,t,:] @ Win[:,n] ----------------

__launch_bounds__(256, 1)
__global__ void proj_gemm(const f16* __restrict__ A, const f16* __restrict__ Bt,
                          float* __restrict__ U) {
  __shared__ f16 As[128 * 32];
  __shared__ f16 Bs[128 * 32];
  const int tid = threadIdx.x;
  const int wv = tid >> 6, l = tid & 63;
  const int m0 = blockIdx.x * 128, n0 = blockIdx.y * 128;
  const int wm = wv >> 1, wn = wv & 1;
  const int srow = tid >> 2, sc = tid & 3;
  const int r = l & 15, kb = l >> 4;
  f32x4 acc[4][4] = {};

  for (int k0 = 0; k0 < EE; k0 += 32) {
    __syncthreads();
#pragma unroll
    for (int q = 0; q < 2; ++q) {
      const int row = q * 64 + srow;
      const int cc = sc ^ (row & 3);   // source pre-swizzle -> swizzled linear LDS
      gload16(A + (size_t)(m0 + row) * EE + k0 + cc * 8,
              (char*)As + q * 4096 + wv * 1024);
      gload16(Bt + (size_t)(n0 + row) * EE + k0 + cc * 8,
              (char*)Bs + q * 4096 + wv * 1024);
    }
    __syncthreads();
    f16x8 af[4], bf[4];
#pragma unroll
    for (int mi = 0; mi < 4; ++mi) {
      const int row = wm * 64 + mi * 16 + r;
      af[mi] = *(const f16x8*)&As[row * 32 + ((kb ^ (row & 3)) * 8)];
    }
#pragma unroll
    for (int ni = 0; ni < 4; ++ni) {
      const int row = wn * 64 + ni * 16 + r;
      bf[ni] = *(const f16x8*)&Bs[row * 32 + ((kb ^ (row & 3)) * 8)];
    }
#pragma unroll
    for (int mi = 0; mi < 4; ++mi)
#pragma unroll
      for (int ni = 0; ni < 4; ++ni)
        acc[mi][ni] = __builtin_amdgcn_mfma_f32_16x16x32_f16(af[mi], bf[ni], acc[mi][ni], 0, 0, 0);
  }
  const int rb = kb * 4;
#pragma unroll
  for (int mi = 0; mi < 4; ++mi)
#pragma unroll
    for (int ni = 0; ni < 4; ++ni)
#pragma unroll
      for (int j = 0; j < 4; ++j) {
        const int m = m0 + wm * 64 + mi * 16 + rb + j;   // token index (b*512 + t)
        const int n = n0 + wn * 64 + ni * 16 + r;
        const int b = m >> 9, t = m & 511;
        U[(size_t)(t * BB + b) * RR + n] = acc[mi][ni][j];
      }
}

// ---------------- the sequential reservoir scan ----------------

__device__ __forceinline__ void gbar(unsigned* bar, int t, int tid) {
  __syncthreads();  // all WG stores complete (vmcnt(0) before barrier)
  if (tid == 0) {
    __hip_atomic_fetch_add(&bar[t], 1u, __ATOMIC_RELEASE, __HIP_MEMORY_SCOPE_AGENT);
    while (__hip_atomic_load(&bar[t], __ATOMIC_RELAXED, __HIP_MEMORY_SCOPE_AGENT) < NWG)
      __builtin_amdgcn_s_sleep(2);
  }
  __syncthreads();
  __builtin_amdgcn_fence(__ATOMIC_ACQUIRE, "agent");
}

__launch_bounds__(512, 1)
__global__ void scan_kernel(const float* __restrict__ R, const float* __restrict__ U,
                            f16* __restrict__ S, unsigned* __restrict__ bar) {
  __shared__ f16 Rt[CPW * RR];   // 32 cols x 2048 rows, transposed [n][k], 128 KB
  const int g = blockIdx.x;
  const int tid = threadIdx.x;
  const int nbase = g * CPW;

  // prologue: load this WG's R column slice, transpose + XOR-swizzle into LDS
  {
    const int cidx = tid & 31;     // column within slice
    const int kst = tid >> 5;      // 0..15
    const int sw = (cidx & 7) << 3;
    for (int k = kst; k < RR; k += 16) {
      float v = R[(size_t)k * RR + nbase + cidx];
      Rt[(cidx * RR + k) ^ sw] = (f16)v;
    }
  }

  // step 0: state0 = 0 -> state1 = tanh(u0); write own column slice
  for (int i = tid; i < BB * CPW; i += 512) {
    const int m = i >> 5, cl = i & 31;
    S[(size_t)m * RR + nbase + cl] = (f16)fast_tanh(U[(size_t)m * RR + nbase + cl]);
  }
  gbar(bar, 0, tid);

  const int wv = tid >> 6, l = tid & 63;
  const int mt = wv >> 1, nt = wv & 1;      // 4 m-tiles x 2 n-tiles = 8 waves
  const int r = l & 15, kb = l >> 4;
  const int mrow = mt * 16 + r;             // A row (batch)
  const int nl = nt * 16 + r;               // B col within slice
  const int bsw = (nl & 7) << 3;
  const int belem0 = nl * RR + kb * 8;
  const int coln = nbase + nt * 16 + r;     // D col (global)
  const int rb = kb * 4;

  for (int t = 1; t < TT; ++t) {
    const f16* Sprev = S + (size_t)((t + 1) & 1) * (BB * RR);
    f16* Snext = S + (size_t)(t & 1) * (BB * RR);
    const f16* arow = Sprev + (size_t)mrow * RR + kb * 8;
    f32x4 acc = {0.f, 0.f, 0.f, 0.f};
#pragma unroll 8
    for (int k0 = 0; k0 < RR; k0 += 32) {
      f16x8 a = *(const f16x8*)(arow + k0);
      f16x8 b = *(const f16x8*)&Rt[(belem0 + k0) ^ bsw];
      acc = __builtin_amdgcn_mfma_f32_16x16x32_f16(a, b, acc, 0, 0, 0);
    }
    const float* ut = U + (size_t)t * (BB * RR);
#pragma unroll
    for (int j = 0; j < 4; ++j) {
      const int m = mt * 16 + rb + j;
      float v = acc[j] + ut[(size_t)m * RR + coln];
      Snext[(size_t)m * RR + coln] = (f16)fast_tanh(v);
    }
    if (t + 1 < TT) gbar(bar, t, tid);
  }
}

// ---------------- LayerNorm ----------------

__launch_bounds__(256, 1)
__global__ void ln_kernel(const f16* __restrict__ Sfin, const float* __restrict__ gamma,
                          const float* __restrict__ beta, float* __restrict__ out) {
  const int b = blockIdx.x;
  const int tid = threadIdx.x;
  const f16* row = Sfin + (size_t)b * RR;
  float vals[8];
  float lsum = 0.f, lsq = 0.f;
#pragma unroll
  for (int i = 0; i < 8; ++i) {
    float v = (float)row[tid + i * 256];
    vals[i] = v; lsum += v; lsq += v * v;
  }
#pragma unroll
  for (int off = 32; off >= 1; off >>= 1) {
    lsum += __shfl_xor(lsum, off);
    lsq  += __shfl_xor(lsq, off);
  }
  __shared__ float ps[4], pq[4];
  __shared__ float mu_s, rstd_s;
  const int wv = tid >> 6, l = tid & 63;
  if (l == 0) { ps[wv] = lsum; pq[wv] = lsq; }
  __syncthreads();
  if (tid == 0) {
    float s = 0.f, q = 0.f;
    for (int i = 0; i < 4; ++i) { s += ps[i]; q += pq[i]; }
    const float mu = s / RR;
    const float var = q / RR - mu * mu;
    mu_s = mu; rstd_s = rsqrtf(var + 1e-5f);
  }
  __syncthreads();
  const float mu = mu_s, rstd = rstd_s;
#pragma unroll
  for (int i = 0; i < 8; ++i) {
    const int idx = tid + i * 256;
    out[(size_t)b * RR + idx] = (vals[i] - mu) * rstd * gamma[idx] + beta[idx];
  }
}

// ---------------- launch ----------------

extern "C" void kernel_launch(void* const* d_in, const int* in_sizes, int n_in,
                              void* d_out, int out_size, void* d_ws, size_t ws_size,
                              hipStream_t stream) {
  const int*   x     = (const int*)d_in[0];
  const float* ew    = (const float*)d_in[1];
  const float* Rm    = (const float*)d_in[2];
  const float* Win   = (const float*)d_in[3];
  const float* gamma = (const float*)d_in[4];
  const float* beta  = (const float*)d_in[5];

  const size_t U_OFF   = 0;                           // fp32  512*64*2048*4 = 268435456
  const size_t EMB_OFF = 268435456;                   // fp16  32768*512*2   =  33554432
  const size_t WT_OFF  = EMB_OFF + 33554432;          // fp16  2048*512*2    =   2097152
  const size_t S_OFF   = WT_OFF + 2097152;            // fp16  2*64*2048*2   =    524288
  const size_t BAR_OFF = S_OFF + 524288;              // u32   512*4
  const size_t NEED    = BAR_OFF + 2048;
  if (ws_size < NEED) {   // signal: leave output zeroed (distinctive absmax)
    hipMemsetAsync(d_out, 0, (size_t)out_size * 4, stream);
    return;
  }
  char* ws = (char*)d_ws;
  float*    Ubuf = (float*)(ws + U_OFF);
  f16*      emb  = (f16*)(ws + EMB_OFF);
  f16*      WinT = (f16*)(ws + WT_OFF);
  f16*      Sbuf = (f16*)(ws + S_OFF);
  unsigned* bar  = (unsigned*)(ws + BAR_OFF);

  hipMemsetAsync(bar, 0, TT * sizeof(unsigned), stream);
  prep_emb<<<BB * TT, 128, 0, stream>>>(x, ew, emb);
  prep_winT<<<(EE * RR) / 256, 256, 0, stream>>>(Win, WinT);
  proj_gemm<<<dim3((BB * TT) / 128, RR / 128), 256, 0, stream>>>(emb, WinT, Ubuf);
  scan_kernel<<<NWG, 512, 0, stream>>>(Rm, Ubuf, Sbuf, bar);
  ln_kernel<<<BB, 256, 0, stream>>>(Sbuf + (size_t)BB * RR, gamma, beta, (float*)d_out);
}